// Round 7
// baseline (200.184 us; speedup 1.0000x reference)
//
#include <hip/hip_runtime.h>
#include <hip/hip_bf16.h>

#define D_DIM 768
#define B_DIM 8192
#define NT 64           // tile grid dim (8192/128)
#define NTILES 2080     // NT*(NT+1)/2 upper-triangle tiles
#define BM 128

typedef __attribute__((ext_vector_type(8))) short short8;
typedef __attribute__((ext_vector_type(4))) float f32x4;
typedef __attribute__((ext_vector_type(2))) float f32x2;
typedef __attribute__((ext_vector_type(4))) unsigned short ushort4v;

// ws layout (bytes)
#define WS_XB   0                               // bf16[8192*768]   = 12,582,912
#define WS_SQ   12582912                        // float[8192]      = 32,768
#define WS_CAND 12615680                        // float[8192*64*6] = 12,582,912
#define WS_ACC  25198592                        // float[1]
#define WS_TKT  25198596                        // uint[1]

__device__ __forceinline__ void gl_lds16(const void* g, void* lds) {
  __builtin_amdgcn_global_load_lds(
      (const __attribute__((address_space(1))) unsigned int*)g,
      (__attribute__((address_space(3))) unsigned int*)lds, 16, 0, 0);
}

// branchless: maintain v[0..5] = six smallest seen, sorted ascending.
__device__ __forceinline__ void ins6(float c, float* v) {
  v[5] = fminf(v[5], c);
#pragma unroll
  for (int s = 5; s > 0; --s) {
    float lo = fminf(v[s - 1], v[s]);
    float hi = fmaxf(v[s - 1], v[s]);
    v[s - 1] = lo;
    v[s] = hi;
  }
}

// band-blocked triangle order (16x16-tile blocks, rt-major inside): L2 working
// set ~3.3 MB. g in [0,2080).
__device__ __forceinline__ void tile_decode(int g, int& rt, int& ct) {
  int base = 0;
  for (int s = 0; s < 4; ++s) {
    for (int cb = s; cb < 4; ++cb) {
      const int sz = (cb == s) ? 136 : 256;
      if (g < base + sz) {
        int loc = g - base;
        if (cb == s) {
          int r = 0;
          while (loc >= 16 - r) {
            loc -= 16 - r;
            ++r;
          }
          rt = s * 16 + r;
          ct = cb * 16 + r + loc;
        } else {
          rt = s * 16 + (loc >> 4);
          ct = cb * 16 + (loc & 15);
        }
        return;
      }
      base += sz;
    }
  }
  rt = 0;
  ct = 0;
}

// kernel 1: cast fp32 -> bf16 (vectorized), row sum-of-squares of bf16 values.
__global__ __launch_bounds__(256) void cast_sq_kernel(
    const float* __restrict__ x, unsigned short* __restrict__ xb,
    float* __restrict__ sq, float* __restrict__ acc,
    unsigned int* __restrict__ tkt) {
  const int t = threadIdx.x;
  const int w = t >> 6, lane = t & 63;
  const int row = blockIdx.x * 4 + w;
  if (blockIdx.x == 0) {
    if (t == 0) acc[0] = 0.0f;
    if (t == 1) tkt[0] = 0u;
  }
  const f32x4* xr = (const f32x4*)(x + (size_t)row * D_DIM);
  ushort4v* xbr = (ushort4v*)(xb + (size_t)row * D_DIM);
  float s = 0.0f;
#pragma unroll
  for (int c = 0; c < 3; ++c) {
    const int idx = c * 64 + lane;
    f32x4 v = xr[idx];
    ushort4v u;
#pragma unroll
    for (int e = 0; e < 4; ++e) {
      __hip_bfloat16 h = __float2bfloat16(v[e]);
      unsigned short us;
      __builtin_memcpy(&us, &h, 2);
      u[e] = us;
      float vb = __bfloat162float(h);
      s += vb * vb;
    }
    xbr[idx] = u;
  }
#pragma unroll
  for (int off = 32; off > 0; off >>= 1) s += __shfl_down(s, off, 64);
  if (lane == 0) sq[row] = s;
}

// ------- kernel 2: symmetric 128x128 tiles, 2-wave fat blocks, ring-of-4 -------
// Wave tile 64x128 (rows split): 12 ds_read_b128 feed 32 MFMA per K=32 section
// (vs 8 reads / 16 MFMA at 64x64) -> 1.33x less LDS-read per FLOP. The round-4
// profile shows LDS read BW (~770 cyc/section/CU) is the binding pipe.
// 64 KiB LDS -> 2 independent blocks/CU (TLP overlap, no cross-block barriers).
// Ring-of-4 16KB slots, 8 loads/section, steady VMW(16) (lead-2 ~1400 cyc),
// drain 16/8/0 at the tail only. Per-tile launch (2080 blocks), band-blocked
// XCD decode (FETCH ~45 MB, proven round 4).
#define ASL(s) ((s) * 16384)
#define BSL(s) ((s) * 16384 + 8192)
#define VMW(N) asm volatile("s_waitcnt vmcnt(" #N ")" ::: "memory")
#define BAR()                         \
  {                                   \
    asm volatile("" ::: "memory");    \
    __builtin_amdgcn_s_barrier();     \
    asm volatile("" ::: "memory");    \
  }

__global__ __launch_bounds__(128, 1) void knn_gemm_kernel(
    const unsigned short* __restrict__ xb, const float* __restrict__ sq,
    float* __restrict__ cand) {
  __shared__ __align__(16) char smem[65536];
  const int t = threadIdx.x;
  const int lane = t & 63, w = t >> 6;  // 2 waves; wave w owns rows w*64..+63
  const int quad = lane >> 4, m16 = lane & 15;

  // XCD chunking (2080 = 8*260, bijective) + band-blocked decode
  const int g = (blockIdx.x & 7) * (NTILES / 8) + (blockIdx.x >> 3);
  int rt, ct;
  tile_decode(g, rt, ct);
  const bool offdiag = (ct > rt);
  const int rowBase = rt * BM, colBase = ct * BM;

  // staging: thread t -> LDS rows R0, R0+32, R0+64, R0+96; lds seg t&3.
  // swizzle: lds slot (R, s) holds global seg s ^ ((R>>1)&3); invariant under
  // R += 32 so sg is shared by all 4 calls.
  const int R0 = t >> 2;
  const int sg = (t & 3) ^ ((t >> 3) & 3);
  const unsigned short* pA = xb + (size_t)(rowBase + R0) * D_DIM + sg * 8;
  const unsigned short* pB = xb + (size_t)(colBase + R0) * D_DIM + sg * 8;

  // fragment read: byte = R*64 + (quad ^ ((R>>1)&3))*16; (R>>1)&3 == (m16>>1)&3
  const int laneOff = ((quad ^ ((m16 >> 1) & 3)) << 4) + m16 * 64;
  const int aOff = w * 4096 + laneOff;  // wave's 64-row half of A
  const int bOff = laneOff;             // all 128 cols of B

  float rsq[16];
#pragma unroll
  for (int i = 0; i < 4; ++i)
#pragma unroll
    for (int r = 0; r < 4; ++r)
      rsq[i * 4 + r] = sq[rowBase + w * 64 + i * 16 + quad * 4 + r];
  float csq[8];
#pragma unroll
  for (int j = 0; j < 8; ++j) csq[j] = sq[colBase + j * 16 + m16];

  f32x4 acv[4][8];
  const f32x4 zero = {0.0f, 0.0f, 0.0f, 0.0f};
#pragma unroll
  for (int i = 0; i < 4; ++i)
#pragma unroll
    for (int j = 0; j < 8; ++j) acv[i][j] = zero;

#define STAGE(P, EOFF, REGION)                                     \
  {                                                                \
    _Pragma("unroll") for (int q = 0; q < 4; ++q)                  \
        gl_lds16((P) + (EOFF) + q * 32 * D_DIM,                    \
                 smem + (REGION) + q * 2048 + t * 16);             \
  }

  short8 aF[4], bF[8];
#define LDA(BASE)                                                            \
  {                                                                          \
    _Pragma("unroll") for (int ii = 0; ii < 4; ++ii)                         \
        aF[ii] = *(const short8*)(smem + (BASE) + ii * 1024 + aOff);         \
  }
#define LDB(BASE)                                                            \
  {                                                                          \
    _Pragma("unroll") for (int j = 0; j < 8; ++j)                            \
        bF[j] = *(const short8*)(smem + (BASE) + j * 1024 + bOff);           \
  }
#define MFMA32                                                               \
  {                                                                          \
    __builtin_amdgcn_s_setprio(1);                                           \
    _Pragma("unroll") for (int ii = 0; ii < 4; ++ii)                         \
        _Pragma("unroll") for (int j = 0; j < 8; ++j)                        \
            acv[ii][j] = __builtin_amdgcn_mfma_f32_16x16x32_bf16(            \
                aF[ii], bF[j], acv[ii][j], 0, 0, 0);                         \
    __builtin_amdgcn_s_setprio(0);                                           \
  }

  // prologue: sections 0..2 -> slots 0..2 (24 loads in flight)
  STAGE(pA, 0, ASL(0));
  STAGE(pB, 0, BSL(0));
  STAGE(pA, 32, ASL(1));
  STAGE(pB, 32, BSL(1));
  STAGE(pA, 64, ASL(2));
  STAGE(pB, 64, BSL(2));

  // sections 0..19: consume slot s&3, stage s+3 into slot (s+3)&3
  for (int a = 0; a < 5; ++a) {
#pragma unroll
    for (int i = 0; i < 4; ++i) {
      VMW(16);
      BAR();
      const int s = a * 4 + i;
      STAGE(pA, (s + 3) * 32, ASL((i + 3) & 3));
      STAGE(pB, (s + 3) * 32, BSL((i + 3) & 3));
      LDA(ASL(i));
      LDB(BSL(i));
      MFMA32;
    }
  }
  // s20 (slot 0), stages s23 -> slot 3
  VMW(16);
  BAR();
  STAGE(pA, 23 * 32, ASL(3));
  STAGE(pB, 23 * 32, BSL(3));
  LDA(ASL(0));
  LDB(BSL(0));
  MFMA32;
  // s21..s23: counted drain
  VMW(16);
  BAR();
  LDA(ASL(1));
  LDB(BSL(1));
  MFMA32;
  VMW(8);
  BAR();
  LDA(ASL(2));
  LDB(BSL(2));
  MFMA32;
  VMW(0);
  BAR();
  LDA(ASL(3));
  LDB(BSL(3));
  MFMA32;

  // ---------------- epilogue: 4 groups of 32 rows ----------------
  float* distS = (float*)smem;            // [32][132] f32
  float* rsqS = (float*)(smem + 16896);   // [32] f32
  float colrun[6];
#pragma unroll
  for (int q = 0; q < 6; ++q) colrun[q] = 1e30f;

#pragma unroll
  for (int gg = 0; gg < 4; ++gg) {
    BAR();
    if ((gg >> 1) == w) {
      const int i0 = (gg & 1) * 2;
      // row-key = csq[col] - 2G (row-constant rsq added at write; order-invariant)
#pragma unroll
      for (int ii = 0; ii < 2; ++ii)
#pragma unroll
        for (int j = 0; j < 8; ++j)
#pragma unroll
          for (int r = 0; r < 4; ++r)
            distS[(ii * 16 + quad * 4 + r) * 132 + j * 16 + m16] =
                csq[j] - 2.0f * acv[i0 + ii][j][r];
      if (m16 == 0) {
#pragma unroll
        for (int ii = 0; ii < 2; ++ii)
#pragma unroll
          for (int r = 0; r < 4; ++r)
            rsqS[ii * 16 + quad * 4 + r] = rsq[(i0 + ii) * 4 + r];
      }
    }
    BAR();
    // row select: 4 thr/row x 32 cols, rotated chunk start (bank-friendly)
    const int row_l = t >> 2, seg = t & 3;
    const float* drow = distS + row_l * 132 + seg * 32;
    float v[6];
#pragma unroll
    for (int q = 0; q < 6; ++q) v[q] = 1e30f;
#pragma unroll
    for (int k = 0; k < 8; ++k) {
      f32x4 dv = *(const f32x4*)(drow + ((k + seg) & 7) * 4);
      ins6(dv[0], v);
      ins6(dv[1], v);
      ins6(dv[2], v);
      ins6(dv[3], v);
    }
#pragma unroll
    for (int st = 1; st <= 2; st <<= 1) {
      float o[6];
#pragma unroll
      for (int q = 0; q < 6; ++q) o[q] = __shfl_xor(v[q], st, 64);
#pragma unroll
      for (int q = 0; q < 6; ++q) ins6(o[q], v);
    }
    if (seg == 0) {
      const int grow = rowBase + gg * 32 + row_l;
      const float rq = rsqS[row_l];
      float* o = cand + (size_t)(grow * NT + ct) * 6;
      f32x2 w0 = {fmaxf(v[0] + rq, 0.0f), fmaxf(v[1] + rq, 0.0f)};
      f32x2 w1 = {fmaxf(v[2] + rq, 0.0f), fmaxf(v[3] + rq, 0.0f)};
      f32x2 w2 = {fmaxf(v[4] + rq, 0.0f), fmaxf(v[5] + rq, 0.0f)};
      *(f32x2*)o = w0;
      *(f32x2*)(o + 2) = w1;
      *(f32x2*)(o + 4) = w2;
    }
    // column partial (off-diagonal only): thread t owns tile column t.
    // key = distS + rsq[row] = full d^2; 2 lanes/bank (col, col+64) = free.
    if (offdiag) {
#pragma unroll
      for (int r = 0; r < 32; ++r) ins6(distS[r * 132 + t] + rsqS[r], colrun);
    }
  }
  if (offdiag) {
    const int colg = colBase + t;
    float* o = cand + (size_t)(colg * NT + rt) * 6;
    f32x2 w0 = {fmaxf(colrun[0], 0.0f), fmaxf(colrun[1], 0.0f)};
    f32x2 w1 = {fmaxf(colrun[2], 0.0f), fmaxf(colrun[3], 0.0f)};
    f32x2 w2 = {fmaxf(colrun[4], 0.0f), fmaxf(colrun[5], 0.0f)};
    *(f32x2*)o = w0;
    *(f32x2*)(o + 2) = w1;
    *(f32x2*)(o + 4) = w2;
  }
}

// kernel 3: per-row merge of 64 chunk-candidates -> sqrt -> log -> global sum,
// with fused finalize via ticket (last block writes the output).
__global__ __launch_bounds__(256) void knn_merge_kernel(
    const float* __restrict__ cand, float* __restrict__ acc,
    unsigned int* __restrict__ tkt, float* __restrict__ out) {
  const int t = threadIdx.x;
  const int r = blockIdx.x * 32 + (t >> 3);
  const float* cr = cand + (size_t)r * (NT * 6) + (size_t)(t & 7) * 48;
  float v[6];
#pragma unroll
  for (int s = 0; s < 6; ++s) v[s] = 1e30f;
#pragma unroll
  for (int c = 0; c < 12; ++c) {
    f32x4 dv = *(const f32x4*)(cr + c * 4);
    ins6(dv[0], v);
    ins6(dv[1], v);
    ins6(dv[2], v);
    ins6(dv[3], v);
  }
#pragma unroll
  for (int st = 1; st <= 4; st <<= 1) {
    float o[6];
#pragma unroll
    for (int q = 0; q < 6; ++q) o[q] = __shfl_xor(v[q], st, 64);
#pragma unroll
    for (int q = 0; q < 6; ++q) ins6(o[q], v);
  }
  float term = 0.0f;
  if ((t & 7) == 0) {
    // v sorted ascending on d^2: v[0] = self (0); knn_mean = mean of sqrt(v[1..5])
    const float mean =
        (sqrtf(v[1]) + sqrtf(v[2]) + sqrtf(v[3]) + sqrtf(v[4]) + sqrtf(v[5])) * 0.2f;
    term = logf(mean + 1e-8f);
  }
#pragma unroll
  for (int off = 32; off > 0; off >>= 1) term += __shfl_down(term, off, 64);
  __shared__ float red[4];
  if ((t & 63) == 0) red[t >> 6] = term;
  __syncthreads();
  if (t == 0) {
    atomicAdd(acc, red[0] + red[1] + red[2] + red[3]);
    __threadfence();
    const unsigned int tk = atomicAdd(tkt, 1u);
    if (tk == (B_DIM / 32) - 1) {
      const float total = atomicAdd(acc, 0.0f);  // coherent read of final sum
      out[0] = -total * (1.0f / 8192.0f);
    }
  }
}

extern "C" void kernel_launch(void* const* d_in, const int* in_sizes, int n_in,
                              void* d_out, int out_size, void* d_ws, size_t ws_size,
                              hipStream_t stream) {
  const float* x = (const float*)d_in[0];
  float* out = (float*)d_out;
  char* ws = (char*)d_ws;
  unsigned short* xb = (unsigned short*)(ws + WS_XB);
  float* sq = (float*)(ws + WS_SQ);
  float* cand = (float*)(ws + WS_CAND);
  float* acc = (float*)(ws + WS_ACC);
  unsigned int* tkt = (unsigned int*)(ws + WS_TKT);

  cast_sq_kernel<<<B_DIM / 4, 256, 0, stream>>>(x, xb, sq, acc, tkt);
  knn_gemm_kernel<<<NTILES, 128, 0, stream>>>(xb, sq, cand);
  knn_merge_kernel<<<B_DIM / 32, 256, 0, stream>>>(cand, acc, tkt, out);
}

// Round 8
// 155.631 us; speedup vs baseline: 1.2863x; 1.2863x over previous
//
#include <hip/hip_runtime.h>
#include <hip/hip_bf16.h>

#define D_DIM 768
#define B_DIM 8192
#define NT 64           // tile grid dim (8192/128)
#define NTILES 2080     // NT*(NT+1)/2 upper-triangle tiles
#define BM 128

typedef __attribute__((ext_vector_type(8))) short short8;
typedef __attribute__((ext_vector_type(4))) float f32x4;
typedef __attribute__((ext_vector_type(2))) float f32x2;
typedef __attribute__((ext_vector_type(4))) unsigned short ushort4v;

// ws layout (bytes)
#define WS_XB   0                               // bf16[8192*768]   = 12,582,912
#define WS_SQ   12582912                        // float[8192]      = 32,768
#define WS_CAND 12615680                        // float[8192*64*6] = 12,582,912
#define WS_ACC  25198592                        // float[1]
#define WS_TKT  25198596                        // uint[1]

__device__ __forceinline__ void gl_lds16(const void* g, void* lds) {
  __builtin_amdgcn_global_load_lds(
      (const __attribute__((address_space(1))) unsigned int*)g,
      (__attribute__((address_space(3))) unsigned int*)lds, 16, 0, 0);
}

// branchless: maintain v[0..5] = six smallest seen, sorted ascending.
__device__ __forceinline__ void ins6(float c, float* v) {
  v[5] = fminf(v[5], c);
#pragma unroll
  for (int s = 5; s > 0; --s) {
    float lo = fminf(v[s - 1], v[s]);
    float hi = fmaxf(v[s - 1], v[s]);
    v[s - 1] = lo;
    v[s] = hi;
  }
}

// band-blocked triangle order (16x16-tile blocks, rt-major inside): L2 working
// set ~3.3 MB. g in [0,2080).
__device__ __forceinline__ void tile_decode(int g, int& rt, int& ct) {
  int base = 0;
  for (int s = 0; s < 4; ++s) {
    for (int cb = s; cb < 4; ++cb) {
      const int sz = (cb == s) ? 136 : 256;
      if (g < base + sz) {
        int loc = g - base;
        if (cb == s) {
          int r = 0;
          while (loc >= 16 - r) {
            loc -= 16 - r;
            ++r;
          }
          rt = s * 16 + r;
          ct = cb * 16 + r + loc;
        } else {
          rt = s * 16 + (loc >> 4);
          ct = cb * 16 + (loc & 15);
        }
        return;
      }
      base += sz;
    }
  }
  rt = 0;
  ct = 0;
}

// kernel 1: cast fp32 -> bf16 (vectorized), row sum-of-squares of bf16 values.
__global__ __launch_bounds__(256) void cast_sq_kernel(
    const float* __restrict__ x, unsigned short* __restrict__ xb,
    float* __restrict__ sq, float* __restrict__ acc,
    unsigned int* __restrict__ tkt) {
  const int t = threadIdx.x;
  const int w = t >> 6, lane = t & 63;
  const int row = blockIdx.x * 4 + w;
  if (blockIdx.x == 0) {
    if (t == 0) acc[0] = 0.0f;
    if (t == 1) tkt[0] = 0u;
  }
  const f32x4* xr = (const f32x4*)(x + (size_t)row * D_DIM);
  ushort4v* xbr = (ushort4v*)(xb + (size_t)row * D_DIM);
  float s = 0.0f;
#pragma unroll
  for (int c = 0; c < 3; ++c) {
    const int idx = c * 64 + lane;
    f32x4 v = xr[idx];
    ushort4v u;
#pragma unroll
    for (int e = 0; e < 4; ++e) {
      __hip_bfloat16 h = __float2bfloat16(v[e]);
      unsigned short us;
      __builtin_memcpy(&us, &h, 2);
      u[e] = us;
      float vb = __bfloat162float(h);
      s += vb * vb;
    }
    xbr[idx] = u;
  }
#pragma unroll
  for (int off = 32; off > 0; off >>= 1) s += __shfl_down(s, off, 64);
  if (lane == 0) sq[row] = s;
}

// ------- kernel 2: symmetric 128x128 tiles, ring-of-3, 3 blocks/CU -------
// Round-4 core (best measured: 93 us): 4 waves 2x2, wave tile 64x64, seg swizzle,
// per-tile launch, band-blocked XCD decode. Changes: ring-of-3 (48 KiB) -> 3
// blocks/CU = 12 waves (3/SIMD) for stall overlap; epilogue = 2 groups of 64 rows
// with split duty (t<128 row-side 2thr/row, t>=128 col-side) to cut ins6+merge
// VALU ~35%.
#define ASL3(s) ((s) * 16384)
#define BSL3(s) ((s) * 16384 + 8192)
#define VMW(N) asm volatile("s_waitcnt vmcnt(" #N ")" ::: "memory")
#define BAR()                         \
  {                                   \
    asm volatile("" ::: "memory");    \
    __builtin_amdgcn_s_barrier();     \
    asm volatile("" ::: "memory");    \
  }

__global__ __launch_bounds__(256, 3) void knn_gemm_kernel(
    const unsigned short* __restrict__ xb, const float* __restrict__ sq,
    float* __restrict__ cand) {
  __shared__ __align__(16) char smem[49152];
  const int t = threadIdx.x;
  const int lane = t & 63, w = t >> 6;
  const int wm = w >> 1, wn = w & 1;  // 2x2 wave grid; wave tile 64x64
  const int quad = lane >> 4, m16 = lane & 15;

  // XCD chunking (2080 = 8*260, bijective) + band-blocked decode
  const int g = (blockIdx.x & 7) * (NTILES / 8) + (blockIdx.x >> 3);
  int rt, ct;
  tile_decode(g, rt, ct);
  const bool offdiag = (ct > rt);
  const int rowBase = rt * BM, colBase = ct * BM;

  // staging: thread t -> LDS rows R0, R0+64; lds seg t&3.
  // swizzle: lds slot (R, s) holds global seg s ^ ((R>>1)&3)
  const int R0 = t >> 2;
  const int sg = (t & 3) ^ ((t >> 3) & 3);
  const unsigned short* pA = xb + (size_t)(rowBase + R0) * D_DIM + sg * 8;
  const unsigned short* pB = xb + (size_t)(colBase + R0) * D_DIM + sg * 8;

  // fragment read: byte = R*64 + (quad ^ ((R>>1)&3))*16; (R>>1)&3 == (m16>>1)&3
  const int laneOff = ((quad ^ ((m16 >> 1) & 3)) << 4) + m16 * 64;
  const int aOff = wm * 4096 + laneOff;
  const int bOff = wn * 4096 + laneOff;

  float rsq[16];
#pragma unroll
  for (int i = 0; i < 4; ++i)
#pragma unroll
    for (int r = 0; r < 4; ++r)
      rsq[i * 4 + r] = sq[rowBase + wm * 64 + i * 16 + quad * 4 + r];
  float csq[4];
#pragma unroll
  for (int j = 0; j < 4; ++j) csq[j] = sq[colBase + wn * 64 + j * 16 + m16];

  f32x4 acv[4][4];
  const f32x4 zero = {0.0f, 0.0f, 0.0f, 0.0f};
#pragma unroll
  for (int i = 0; i < 4; ++i)
#pragma unroll
    for (int j = 0; j < 4; ++j) acv[i][j] = zero;

#define STAGE(P, EOFF, REGION)                                            \
  {                                                                       \
    gl_lds16((P) + (EOFF), smem + (REGION) + t * 16);                     \
    gl_lds16((P) + (EOFF) + 64 * D_DIM, smem + (REGION) + 4096 + t * 16); \
  }

  short8 aF[4], bF[4];
#define LDA(BASE)                                                            \
  {                                                                          \
    _Pragma("unroll") for (int ii = 0; ii < 4; ++ii)                         \
        aF[ii] = *(const short8*)(smem + (BASE) + ii * 1024 + aOff);         \
  }
#define LDB(BASE)                                                            \
  {                                                                          \
    _Pragma("unroll") for (int j = 0; j < 4; ++j)                            \
        bF[j] = *(const short8*)(smem + (BASE) + j * 1024 + bOff);           \
  }
#define MFMA16                                                               \
  {                                                                          \
    __builtin_amdgcn_s_setprio(1);                                           \
    _Pragma("unroll") for (int ii = 0; ii < 4; ++ii)                         \
        _Pragma("unroll") for (int j = 0; j < 4; ++j)                        \
            acv[ii][j] = __builtin_amdgcn_mfma_f32_16x16x32_bf16(            \
                aF[ii], bF[j], acv[ii][j], 0, 0, 0);                         \
    __builtin_amdgcn_s_setprio(0);                                           \
  }

  // prologue: sections 0,1 -> slots 0,1 (8 loads in flight)
  STAGE(pA, 0, ASL3(0));
  STAGE(pB, 0, BSL3(0));
  STAGE(pA, 32, ASL3(1));
  STAGE(pB, 32, BSL3(1));

  // sections 0..20: consume slot s%3, stage s+2 into slot (s+2)%3 (= the slot
  // consumed at s-1; its ds_reads retired before this barrier)
  for (int a = 0; a < 7; ++a) {
#pragma unroll
    for (int i = 0; i < 3; ++i) {
      VMW(4);
      BAR();
      const int s = a * 3 + i;
      STAGE(pA, (s + 2) * 32, ASL3((i + 2) % 3));
      STAGE(pB, (s + 2) * 32, BSL3((i + 2) % 3));
      LDA(ASL3(i));
      LDB(BSL3(i));
      MFMA16;
    }
  }
  // s21 (slot 0), stages s23 -> slot 2
  VMW(4);
  BAR();
  STAGE(pA, 23 * 32, ASL3(2));
  STAGE(pB, 23 * 32, BSL3(2));
  LDA(ASL3(0));
  LDB(BSL3(0));
  MFMA16;
  // s22, s23: counted drain
  VMW(4);
  BAR();
  LDA(ASL3(1));
  LDB(BSL3(1));
  MFMA16;
  VMW(0);
  BAR();
  LDA(ASL3(2));
  LDB(BSL3(2));
  MFMA16;

  // ---------------- epilogue: 2 groups of 64 rows, split row/col duty ----------------
  float* distS = (float*)smem;             // [64][132] f32 = 33792 B
  float* rsqS = (float*)(smem + 33792);    // [64] f32
  float colrun[6];
#pragma unroll
  for (int q = 0; q < 6; ++q) colrun[q] = 1e30f;

#pragma unroll
  for (int gg = 0; gg < 2; ++gg) {
    BAR();
    if (wm == gg) {
      // row-key = csq[col] - 2G (row-constant rsq added at write; order-invariant)
#pragma unroll
      for (int ii = 0; ii < 4; ++ii)
#pragma unroll
        for (int j = 0; j < 4; ++j)
#pragma unroll
          for (int r = 0; r < 4; ++r)
            distS[(ii * 16 + quad * 4 + r) * 132 + wn * 64 + j * 16 + m16] =
                csq[j] - 2.0f * acv[ii][j][r];
      if (wn == 0 && m16 == 0) {
#pragma unroll
        for (int ii = 0; ii < 4; ++ii)
#pragma unroll
          for (int r = 0; r < 4; ++r)
            rsqS[ii * 16 + quad * 4 + r] = rsq[ii * 4 + r];
      }
    }
    BAR();
    if (t < 128) {
      // row-side: 2 thr/row x 64 cols, single shfl merge with partner t^1
      const int row_l = t >> 1, half = t & 1;
      const float* drow = distS + row_l * 132 + half * 64;
      float v[6];
#pragma unroll
      for (int q = 0; q < 6; ++q) v[q] = 1e30f;
#pragma unroll
      for (int k = 0; k < 16; ++k) {
        f32x4 dv = *(const f32x4*)(drow + k * 4);
        ins6(dv[0], v);
        ins6(dv[1], v);
        ins6(dv[2], v);
        ins6(dv[3], v);
      }
      float o[6];
#pragma unroll
      for (int q = 0; q < 6; ++q) o[q] = __shfl_xor(v[q], 1, 64);
#pragma unroll
      for (int q = 0; q < 6; ++q) ins6(o[q], v);
      if (half == 0) {
        const int grow = rowBase + gg * 64 + row_l;
        const float rq = rsqS[row_l];
        float* o6 = cand + (size_t)(grow * NT + ct) * 6;
        f32x2 w0 = {fmaxf(v[0] + rq, 0.0f), fmaxf(v[1] + rq, 0.0f)};
        f32x2 w1 = {fmaxf(v[2] + rq, 0.0f), fmaxf(v[3] + rq, 0.0f)};
        f32x2 w2 = {fmaxf(v[4] + rq, 0.0f), fmaxf(v[5] + rq, 0.0f)};
        *(f32x2*)o6 = w0;
        *(f32x2*)(o6 + 2) = w1;
        *(f32x2*)(o6 + 4) = w2;
      }
    } else if (offdiag) {
      // col-side: 1 thr/col; key = distS + rsq[row] = full d^2.
      // banks: (4r + col) % 32, 64 cols -> 2 lanes/bank = free.
      const int col = t - 128;
#pragma unroll
      for (int r = 0; r < 64; ++r) ins6(distS[r * 132 + col] + rsqS[r], colrun);
    }
  }
  if (offdiag && t >= 128) {
    const int colg = colBase + (t - 128);
    float* o6 = cand + (size_t)(colg * NT + rt) * 6;
    f32x2 w0 = {fmaxf(colrun[0], 0.0f), fmaxf(colrun[1], 0.0f)};
    f32x2 w1 = {fmaxf(colrun[2], 0.0f), fmaxf(colrun[3], 0.0f)};
    f32x2 w2 = {fmaxf(colrun[4], 0.0f), fmaxf(colrun[5], 0.0f)};
    *(f32x2*)o6 = w0;
    *(f32x2*)(o6 + 2) = w1;
    *(f32x2*)(o6 + 4) = w2;
  }
}

// kernel 3: per-row merge of 64 chunk-candidates -> sqrt -> log -> global sum,
// with fused finalize via ticket (last block writes the output).
__global__ __launch_bounds__(256) void knn_merge_kernel(
    const float* __restrict__ cand, float* __restrict__ acc,
    unsigned int* __restrict__ tkt, float* __restrict__ out) {
  const int t = threadIdx.x;
  const int r = blockIdx.x * 32 + (t >> 3);
  const float* cr = cand + (size_t)r * (NT * 6) + (size_t)(t & 7) * 48;
  float v[6];
#pragma unroll
  for (int s = 0; s < 6; ++s) v[s] = 1e30f;
#pragma unroll
  for (int c = 0; c < 12; ++c) {
    f32x4 dv = *(const f32x4*)(cr + c * 4);
    ins6(dv[0], v);
    ins6(dv[1], v);
    ins6(dv[2], v);
    ins6(dv[3], v);
  }
#pragma unroll
  for (int st = 1; st <= 4; st <<= 1) {
    float o[6];
#pragma unroll
    for (int q = 0; q < 6; ++q) o[q] = __shfl_xor(v[q], st, 64);
#pragma unroll
    for (int q = 0; q < 6; ++q) ins6(o[q], v);
  }
  float term = 0.0f;
  if ((t & 7) == 0) {
    // v sorted ascending on d^2: v[0] = self (0); knn_mean = mean of sqrt(v[1..5])
    const float mean =
        (sqrtf(v[1]) + sqrtf(v[2]) + sqrtf(v[3]) + sqrtf(v[4]) + sqrtf(v[5])) * 0.2f;
    term = logf(mean + 1e-8f);
  }
#pragma unroll
  for (int off = 32; off > 0; off >>= 1) term += __shfl_down(term, off, 64);
  __shared__ float red[4];
  if ((t & 63) == 0) red[t >> 6] = term;
  __syncthreads();
  if (t == 0) {
    atomicAdd(acc, red[0] + red[1] + red[2] + red[3]);
    __threadfence();
    const unsigned int tk = atomicAdd(tkt, 1u);
    if (tk == (B_DIM / 32) - 1) {
      const float total = atomicAdd(acc, 0.0f);  // coherent read of final sum
      out[0] = -total * (1.0f / 8192.0f);
    }
  }
}

extern "C" void kernel_launch(void* const* d_in, const int* in_sizes, int n_in,
                              void* d_out, int out_size, void* d_ws, size_t ws_size,
                              hipStream_t stream) {
  const float* x = (const float*)d_in[0];
  float* out = (float*)d_out;
  char* ws = (char*)d_ws;
  unsigned short* xb = (unsigned short*)(ws + WS_XB);
  float* sq = (float*)(ws + WS_SQ);
  float* cand = (float*)(ws + WS_CAND);
  float* acc = (float*)(ws + WS_ACC);
  unsigned int* tkt = (unsigned int*)(ws + WS_TKT);

  cast_sq_kernel<<<B_DIM / 4, 256, 0, stream>>>(x, xb, sq, acc, tkt);
  knn_gemm_kernel<<<NTILES, 256, 0, stream>>>(xb, sq, cand);
  knn_merge_kernel<<<B_DIM / 32, 256, 0, stream>>>(cand, acc, tkt, out);
}